// Round 4
// baseline (10335.078 us; speedup 1.0000x reference)
//
#include <hip/hip_runtime.h>
#include <math.h>

#define B_ 8
#define N_ 16384
#define M_ 4096
#define D_ 512
#define TPB 1024
#define PPT 16          // N_ / TPB points per thread

#define FEAT_SZ (B_ * M_ * D_)          // 16777216
#define COFF FEAT_SZ                    // coords_out
#define TOFF (FEAT_SZ + 2 * B_ * M_)    // times_out
#define POFF (TOFF + B_ * M_)           // pol_out

// ---------------------------------------------------------------------------
// Kernel 1: farthest point sampling, one block per batch.
// Distance rounding verified in round 2: d2 = fma(dt,dt, fma(dx,dx, dy*dy))
// (LLVM contraction of XLA's unrolled reduce), then sqrt_rn(d2 + 1e-8).
// min tracked in squared domain (sqrt monotone); argmax in sqrt domain with
// first-index tie-break (jnp.argmax semantics).
//
// __launch_bounds__(1024, 4): 4 waves/EU * 4 EU = 16 waves = exactly this one
// block per CU -> VGPR cap 512/4 = 128. Round-3 counters proved that without
// this the compiler targeted 2 blocks/CU (cap 64) and spilled all five
// float[16] arrays to scratch (VGPR_Count=64, 807MB scratch FETCH, ~97%
// per-CU VALUBusy on spill traffic).
// ---------------------------------------------------------------------------
__global__ __launch_bounds__(TPB, 4) void fps_kernel(
    const float* __restrict__ coords, const float* __restrict__ times,
    int* __restrict__ idx_out)
{
    const int b = blockIdx.x;
    const int t = threadIdx.x;
    const float* cb = coords + (size_t)b * N_ * 2;
    const float* tb = times + (size_t)b * N_;

    float px[PPT], py[PPT], pt[PPT], m2[PPT], s[PPT];
#pragma unroll
    for (int j = 0; j < PPT; ++j) {
        int gi = j * TPB + t;
        float2 c2 = *(const float2*)(cb + 2 * (size_t)gi);
        px[j] = c2.x; py[j] = c2.y; pt[j] = tb[gi];
        m2[j] = INFINITY; s[j] = INFINITY;
    }

    __shared__ unsigned long long sh_key[2];

    if (t == 0) {
        idx_out[b * M_] = 0;            // deterministic seed point
        sh_key[0] = 0ULL;
        sh_key[1] = 0ULL;
    }
    // seed point coords: broadcast load (L1/L2-hot after first touch)
    float lx = cb[0], ly = cb[1], lt = tb[0];
    __syncthreads();

    const int lane = t & 63;

    for (int k = 1; k < M_; ++k) {
        float best = -INFINITY;
        int   bi = 0;
#pragma unroll
        for (int j = 0; j < PPT; ++j) {
            float dx = px[j] - lx;
            float dy = py[j] - ly;
            float dt = pt[j] - lt;
            float d2 = __fmaf_rn(dt, dt, __fmaf_rn(dx, dx, __fmul_rn(dy, dy)));
            if (d2 < m2[j]) {
                m2[j] = d2;
                s[j] = __fsqrt_rn(__fadd_rn(d2, 1e-8f));
            }
            if (s[j] > best) { best = s[j]; bi = j * TPB + t; }  // strict >: first index wins
        }

        // pack: max s wins; tie -> max (N-1-idx) = min idx (jnp.argmax first-hit)
        unsigned long long key =
            ((unsigned long long)__float_as_uint(best) << 32) |
            (unsigned)(N_ - 1 - bi);

        // wave (64-lane) max-reduce of the packed key
#pragma unroll
        for (int off = 1; off < 64; off <<= 1) {
            unsigned long long ok = __shfl_xor(key, off);
            if (ok > key) key = ok;
        }
        if (lane == 0) atomicMax(&sh_key[k & 1], key);
        __syncthreads();

        const unsigned long long wk = sh_key[k & 1];
        const int gi = N_ - 1 - (int)(unsigned)(wk & 0xffffffffu);
        if (t == 0) {
            idx_out[b * M_ + k] = gi;
            sh_key[(k + 1) & 1] = 0ULL;   // reset other slot before BAR2: race-free
        }
        // winner's point: same-address broadcast loads, latency hides under BAR2
        lx = cb[2 * gi]; ly = cb[2 * gi + 1]; lt = tb[gi];
        __syncthreads();
    }
}

// ---------------------------------------------------------------------------
// Kernel 2: gather coords/times/polarities at sampled indices.
// ---------------------------------------------------------------------------
__global__ __launch_bounds__(256) void gather_kernel(
    const float* __restrict__ coords, const float* __restrict__ times,
    const float* __restrict__ pol, const int* __restrict__ idx,
    float* __restrict__ out)
{
    int i = blockIdx.x * 256 + threadIdx.x;       // 0 .. B_*M_-1
    if (i >= B_ * M_) return;
    int b = i >> 12;                              // / M_
    int g = b * N_ + idx[i];
    float2 c2 = *(const float2*)(coords + 2 * (size_t)g);
    *(float2*)(out + COFF + 2 * (size_t)i) = c2;
    out[TOFF + i] = times[g];
    out[POFF + i] = pol[g];
}

// ---------------------------------------------------------------------------
// Kernel 3: gathered GEMM + bias.  C[row, o] = features[src(row), :] . W[o, :]
// ---------------------------------------------------------------------------
#define BM 32
#define BN 128
#define BK 32

__global__ __launch_bounds__(256) void proj_kernel(
    const float* __restrict__ features, const float* __restrict__ W,
    const float* __restrict__ bias, const int* __restrict__ idx,
    float* __restrict__ out)
{
    __shared__ float a_lds[BK][BM + 4];
    __shared__ float w_lds[BK][BN];
    __shared__ int   src[BM];

    const int t = threadIdx.x;
    const int rowBase = blockIdx.x * BM;
    const int oBase = blockIdx.y * BN;

    if (t < BM) {
        int row = rowBase + t;
        int b = row >> 12;                // / M_
        src[t] = b * N_ + idx[row];
    }
    __syncthreads();

    const int rt = t >> 5;        // 0..7   -> rows rt*4..rt*4+3
    const int ot = t & 31;        // 0..31  -> outs ot*4..ot*4+3
    const int lr = t >> 3;        // 0..31  staging row / out
    const int lk = (t & 7) * 4;   // 0,4,...,28 staging k

    float c[4][4] = {};

    for (int kc = 0; kc < D_; kc += BK) {
        {
            float4 v = *(const float4*)(features + (size_t)src[lr] * D_ + kc + lk);
            a_lds[lk + 0][lr] = v.x; a_lds[lk + 1][lr] = v.y;
            a_lds[lk + 2][lr] = v.z; a_lds[lk + 3][lr] = v.w;
        }
#pragma unroll
        for (int p = 0; p < 4; ++p) {
            int o = p * 32 + lr;
            float4 v = *(const float4*)(W + (size_t)(oBase + o) * D_ + kc + lk);
            w_lds[lk + 0][o] = v.x; w_lds[lk + 1][o] = v.y;
            w_lds[lk + 2][o] = v.z; w_lds[lk + 3][o] = v.w;
        }
        __syncthreads();

#pragma unroll
        for (int k = 0; k < BK; ++k) {
            float4 af = *(const float4*)&a_lds[k][rt * 4];
            float4 wf = *(const float4*)&w_lds[k][ot * 4];
            float av[4] = { af.x, af.y, af.z, af.w };
            float wv[4] = { wf.x, wf.y, wf.z, wf.w };
#pragma unroll
            for (int ri = 0; ri < 4; ++ri)
#pragma unroll
                for (int oi = 0; oi < 4; ++oi)
                    c[ri][oi] = fmaf(av[ri], wv[oi], c[ri][oi]);
        }
        __syncthreads();
    }

    float4 bv = *(const float4*)(bias + oBase + ot * 4);
    float bvv[4] = { bv.x, bv.y, bv.z, bv.w };
#pragma unroll
    for (int ri = 0; ri < 4; ++ri) {
        int row = rowBase + rt * 4 + ri;
        float4 o4;
        o4.x = c[ri][0] + bvv[0];
        o4.y = c[ri][1] + bvv[1];
        o4.z = c[ri][2] + bvv[2];
        o4.w = c[ri][3] + bvv[3];
        *(float4*)(out + (size_t)row * D_ + oBase + ot * 4) = o4;
    }
}

// ---------------------------------------------------------------------------
// Kernel 4: LayerNorm in place over the proj output. One wave per row.
// ---------------------------------------------------------------------------
__global__ __launch_bounds__(256) void ln_kernel(
    float* __restrict__ out, const float* __restrict__ gamma,
    const float* __restrict__ beta)
{
    const int w = threadIdx.x >> 6;
    const int lane = threadIdx.x & 63;
    const size_t row = (size_t)blockIdx.x * 4 + w;
    float* p = out + row * D_;

    float4 v0 = *(const float4*)(p + lane * 8);
    float4 v1 = *(const float4*)(p + lane * 8 + 4);
    float x[8] = { v0.x, v0.y, v0.z, v0.w, v1.x, v1.y, v1.z, v1.w };

    float sum = 0.f;
#pragma unroll
    for (int i = 0; i < 8; ++i) sum += x[i];
#pragma unroll
    for (int off = 1; off < 64; off <<= 1) sum += __shfl_xor(sum, off);
    const float mu = sum * (1.0f / 512.0f);

    float sq = 0.f;
#pragma unroll
    for (int i = 0; i < 8; ++i) { float d = x[i] - mu; sq = fmaf(d, d, sq); }
#pragma unroll
    for (int off = 1; off < 64; off <<= 1) sq += __shfl_xor(sq, off);
    const float inv = rsqrtf(sq * (1.0f / 512.0f) + 1e-5f);

    float4 g0 = *(const float4*)(gamma + lane * 8);
    float4 g1 = *(const float4*)(gamma + lane * 8 + 4);
    float4 b0 = *(const float4*)(beta + lane * 8);
    float4 b1 = *(const float4*)(beta + lane * 8 + 4);
    float g[8] = { g0.x, g0.y, g0.z, g0.w, g1.x, g1.y, g1.z, g1.w };
    float be[8] = { b0.x, b0.y, b0.z, b0.w, b1.x, b1.y, b1.z, b1.w };

    float y[8];
#pragma unroll
    for (int i = 0; i < 8; ++i) y[i] = fmaf((x[i] - mu) * inv, g[i], be[i]);

    float4 o0 = { y[0], y[1], y[2], y[3] };
    float4 o1 = { y[4], y[5], y[6], y[7] };
    *(float4*)(p + lane * 8) = o0;
    *(float4*)(p + lane * 8 + 4) = o1;
}

// ---------------------------------------------------------------------------
extern "C" void kernel_launch(void* const* d_in, const int* in_sizes, int n_in,
                              void* d_out, int out_size, void* d_ws, size_t ws_size,
                              hipStream_t stream)
{
    const float* features   = (const float*)d_in[0];
    const float* coords     = (const float*)d_in[1];
    const float* times      = (const float*)d_in[2];
    const float* polarities = (const float*)d_in[3];
    const float* W          = (const float*)d_in[4];
    const float* bias       = (const float*)d_in[5];
    const float* gamma      = (const float*)d_in[6];
    const float* beta       = (const float*)d_in[7];
    float* out = (float*)d_out;

    int* idx = (int*)d_ws;                        // B_*M_ ints = 128 KiB scratch

    fps_kernel<<<B_, TPB, 0, stream>>>(coords, times, idx);

    gather_kernel<<<(B_ * M_ + 255) / 256, 256, 0, stream>>>(
        coords, times, polarities, idx, out);

    dim3 pgrid(B_ * M_ / BM, D_ / BN);            // (1024, 4)
    proj_kernel<<<pgrid, 256, 0, stream>>>(features, W, bias, idx, out);

    ln_kernel<<<B_ * M_ / 4, 256, 0, stream>>>(out, gamma, beta);
}

// Round 5
// 10005.857 us; speedup vs baseline: 1.0329x; 1.0329x over previous
//
#include <hip/hip_runtime.h>
#include <math.h>

#define B_ 8
#define N_ 16384
#define M_ 4096
#define D_ 512
#define TPB 1024
#define PPT 16          // N_ / TPB points per thread

#define FEAT_SZ (B_ * M_ * D_)          // 16777216
#define COFF FEAT_SZ                    // coords_out
#define TOFF (FEAT_SZ + 2 * B_ * M_)    // times_out
#define POFF (TOFF + B_ * M_)           // pol_out

#define R16(F) F(0) F(1) F(2) F(3) F(4) F(5) F(6) F(7) \
               F(8) F(9) F(10) F(11) F(12) F(13) F(14) F(15)

// ---------------------------------------------------------------------------
// Kernel 1: farthest point sampling, one block per batch.
// Distance rounding verified in round 2: d2 = fma(dz,dz, fma(dx,dx, dy*dy))
// (LLVM contraction of XLA's unrolled reduce), then sqrt_rn(d2 + 1e-8).
// Min tracked in SQRT domain — s = min(s, sqrt_rn(d2+1e-8)) — which is the
// reference's exact formula (jnp.minimum(dist_min, sqrt(...))); argmax with
// first-index tie-break via packed (s_bits<<32)|(N-1-idx) u64 keys.
//
// Perf-critical: per-point state is 64 MANUALLY NAMED scalars (px0..s15),
// not arrays. Rounds 2-4 proved the array form is never SROA-promoted
// (VGPR_Count stuck at 64, 807MB scratch FETCH = N*12B refetched per iter,
// launch_bounds had zero effect). Named scalars are SSA values — no alloca,
// no scratch. ~85 VGPRs fits the 128 hard cap (1024-thr block = 4 waves/SIMD
// x 128 = full file).
// ---------------------------------------------------------------------------
__global__ __launch_bounds__(TPB, 4) void fps_kernel(
    const float* __restrict__ coords, const float* __restrict__ times,
    int* __restrict__ idx_out)
{
    const int b = blockIdx.x;
    const int t = threadIdx.x;
    const float* cb = coords + (size_t)b * N_ * 2;
    const float* tb = times + (size_t)b * N_;

#define DECLV(i) float px##i, py##i, pt##i, s##i;
    R16(DECLV)
#undef DECLV

#define LOADV(i) { const int gi = (i) * TPB + t;                              \
        const float2 c2 = *(const float2*)(cb + 2 * (size_t)gi);              \
        px##i = c2.x; py##i = c2.y; pt##i = tb[gi]; s##i = INFINITY; }
    R16(LOADV)
#undef LOADV

    __shared__ unsigned long long sh_key[2];

    if (t == 0) {
        idx_out[b * M_] = 0;            // deterministic seed point
        sh_key[0] = 0ULL;
        sh_key[1] = 0ULL;
    }
    // seed point: broadcast load (L1-hot)
    float lx = cb[0], ly = cb[1], lt = tb[0];
    __syncthreads();

    const int lane = t & 63;

    for (int k = 1; k < M_; ++k) {
        float best = -INFINITY;
        int   bi = 0;

#define UPDV(i) {                                                             \
        const float dx = px##i - lx;                                          \
        const float dy = py##i - ly;                                          \
        const float dz = pt##i - lt;                                          \
        const float d2 = __fmaf_rn(dz, dz, __fmaf_rn(dx, dx,                  \
                                                     __fmul_rn(dy, dy)));     \
        const float sn = __fsqrt_rn(__fadd_rn(d2, 1e-8f));                    \
        s##i = fminf(s##i, sn);                                               \
        if (s##i > best) { best = s##i; bi = (i) * TPB + t; } }
        R16(UPDV)
#undef UPDV

        // pack: max s wins; tie -> max (N-1-idx) = min idx (jnp.argmax first-hit)
        unsigned long long key =
            ((unsigned long long)__float_as_uint(best) << 32) |
            (unsigned)(N_ - 1 - bi);

        // wave (64-lane) max-reduce of the packed key
#pragma unroll
        for (int off = 1; off < 64; off <<= 1) {
            unsigned long long ok = __shfl_xor(key, off);
            if (ok > key) key = ok;
        }
        if (lane == 0) atomicMax(&sh_key[k & 1], key);
        __syncthreads();

        const unsigned long long wk = sh_key[k & 1];
        const int gi = N_ - 1 - (int)(unsigned)(wk & 0xffffffffu);
        if (t == 0) {
            idx_out[b * M_ + k] = gi;
            sh_key[(k + 1) & 1] = 0ULL;   // reset other slot before BAR2: race-free
        }
        // winner's point: same-address broadcast loads, latency hides under BAR2
        lx = cb[2 * gi]; ly = cb[2 * gi + 1]; lt = tb[gi];
        __syncthreads();
    }
}

// ---------------------------------------------------------------------------
// Kernel 2: gather coords/times/polarities at sampled indices.
// ---------------------------------------------------------------------------
__global__ __launch_bounds__(256) void gather_kernel(
    const float* __restrict__ coords, const float* __restrict__ times,
    const float* __restrict__ pol, const int* __restrict__ idx,
    float* __restrict__ out)
{
    int i = blockIdx.x * 256 + threadIdx.x;       // 0 .. B_*M_-1
    if (i >= B_ * M_) return;
    int b = i >> 12;                              // / M_
    int g = b * N_ + idx[i];
    float2 c2 = *(const float2*)(coords + 2 * (size_t)g);
    *(float2*)(out + COFF + 2 * (size_t)i) = c2;
    out[TOFF + i] = times[g];
    out[POFF + i] = pol[g];
}

// ---------------------------------------------------------------------------
// Kernel 3: gathered GEMM + bias.  C[row, o] = features[src(row), :] . W[o, :]
// ---------------------------------------------------------------------------
#define BM 32
#define BN 128
#define BK 32

__global__ __launch_bounds__(256) void proj_kernel(
    const float* __restrict__ features, const float* __restrict__ W,
    const float* __restrict__ bias, const int* __restrict__ idx,
    float* __restrict__ out)
{
    __shared__ float a_lds[BK][BM + 4];
    __shared__ float w_lds[BK][BN];
    __shared__ int   src[BM];

    const int t = threadIdx.x;
    const int rowBase = blockIdx.x * BM;
    const int oBase = blockIdx.y * BN;

    if (t < BM) {
        int row = rowBase + t;
        int b = row >> 12;                // / M_
        src[t] = b * N_ + idx[row];
    }
    __syncthreads();

    const int rt = t >> 5;        // 0..7   -> rows rt*4..rt*4+3
    const int ot = t & 31;        // 0..31  -> outs ot*4..ot*4+3
    const int lr = t >> 3;        // 0..31  staging row / out
    const int lk = (t & 7) * 4;   // 0,4,...,28 staging k

    float c[4][4] = {};

    for (int kc = 0; kc < D_; kc += BK) {
        {
            float4 v = *(const float4*)(features + (size_t)src[lr] * D_ + kc + lk);
            a_lds[lk + 0][lr] = v.x; a_lds[lk + 1][lr] = v.y;
            a_lds[lk + 2][lr] = v.z; a_lds[lk + 3][lr] = v.w;
        }
#pragma unroll
        for (int p = 0; p < 4; ++p) {
            int o = p * 32 + lr;
            float4 v = *(const float4*)(W + (size_t)(oBase + o) * D_ + kc + lk);
            w_lds[lk + 0][o] = v.x; w_lds[lk + 1][o] = v.y;
            w_lds[lk + 2][o] = v.z; w_lds[lk + 3][o] = v.w;
        }
        __syncthreads();

#pragma unroll
        for (int k = 0; k < BK; ++k) {
            float4 af = *(const float4*)&a_lds[k][rt * 4];
            float4 wf = *(const float4*)&w_lds[k][ot * 4];
            float av[4] = { af.x, af.y, af.z, af.w };
            float wv[4] = { wf.x, wf.y, wf.z, wf.w };
#pragma unroll
            for (int ri = 0; ri < 4; ++ri)
#pragma unroll
                for (int oi = 0; oi < 4; ++oi)
                    c[ri][oi] = fmaf(av[ri], wv[oi], c[ri][oi]);
        }
        __syncthreads();
    }

    float4 bv = *(const float4*)(bias + oBase + ot * 4);
    float bvv[4] = { bv.x, bv.y, bv.z, bv.w };
#pragma unroll
    for (int ri = 0; ri < 4; ++ri) {
        int row = rowBase + rt * 4 + ri;
        float4 o4;
        o4.x = c[ri][0] + bvv[0];
        o4.y = c[ri][1] + bvv[1];
        o4.z = c[ri][2] + bvv[2];
        o4.w = c[ri][3] + bvv[3];
        *(float4*)(out + (size_t)row * D_ + oBase + ot * 4) = o4;
    }
}

// ---------------------------------------------------------------------------
// Kernel 4: LayerNorm in place over the proj output. One wave per row.
// ---------------------------------------------------------------------------
__global__ __launch_bounds__(256) void ln_kernel(
    float* __restrict__ out, const float* __restrict__ gamma,
    const float* __restrict__ beta)
{
    const int w = threadIdx.x >> 6;
    const int lane = threadIdx.x & 63;
    const size_t row = (size_t)blockIdx.x * 4 + w;
    float* p = out + row * D_;

    float4 v0 = *(const float4*)(p + lane * 8);
    float4 v1 = *(const float4*)(p + lane * 8 + 4);
    float x[8] = { v0.x, v0.y, v0.z, v0.w, v1.x, v1.y, v1.z, v1.w };

    float sum = 0.f;
#pragma unroll
    for (int i = 0; i < 8; ++i) sum += x[i];
#pragma unroll
    for (int off = 1; off < 64; off <<= 1) sum += __shfl_xor(sum, off);
    const float mu = sum * (1.0f / 512.0f);

    float sq = 0.f;
#pragma unroll
    for (int i = 0; i < 8; ++i) { float d = x[i] - mu; sq = fmaf(d, d, sq); }
#pragma unroll
    for (int off = 1; off < 64; off <<= 1) sq += __shfl_xor(sq, off);
    const float inv = rsqrtf(sq * (1.0f / 512.0f) + 1e-5f);

    float4 g0 = *(const float4*)(gamma + lane * 8);
    float4 g1 = *(const float4*)(gamma + lane * 8 + 4);
    float4 b0 = *(const float4*)(beta + lane * 8);
    float4 b1 = *(const float4*)(beta + lane * 8 + 4);
    float g[8] = { g0.x, g0.y, g0.z, g0.w, g1.x, g1.y, g1.z, g1.w };
    float be[8] = { b0.x, b0.y, b0.z, b0.w, b1.x, b1.y, b1.z, b1.w };

    float y[8];
#pragma unroll
    for (int i = 0; i < 8; ++i) y[i] = fmaf((x[i] - mu) * inv, g[i], be[i]);

    float4 o0 = { y[0], y[1], y[2], y[3] };
    float4 o1 = { y[4], y[5], y[6], y[7] };
    *(float4*)(p + lane * 8) = o0;
    *(float4*)(p + lane * 8 + 4) = o1;
}

// ---------------------------------------------------------------------------
extern "C" void kernel_launch(void* const* d_in, const int* in_sizes, int n_in,
                              void* d_out, int out_size, void* d_ws, size_t ws_size,
                              hipStream_t stream)
{
    const float* features   = (const float*)d_in[0];
    const float* coords     = (const float*)d_in[1];
    const float* times      = (const float*)d_in[2];
    const float* polarities = (const float*)d_in[3];
    const float* W          = (const float*)d_in[4];
    const float* bias       = (const float*)d_in[5];
    const float* gamma      = (const float*)d_in[6];
    const float* beta       = (const float*)d_in[7];
    float* out = (float*)d_out;

    int* idx = (int*)d_ws;                        // B_*M_ ints = 128 KiB scratch

    fps_kernel<<<B_, TPB, 0, stream>>>(coords, times, idx);

    gather_kernel<<<(B_ * M_ + 255) / 256, 256, 0, stream>>>(
        coords, times, polarities, idx, out);

    dim3 pgrid(B_ * M_ / BM, D_ / BN);            // (1024, 4)
    proj_kernel<<<pgrid, 256, 0, stream>>>(features, W, bias, idx, out);

    ln_kernel<<<B_ * M_ / 4, 256, 0, stream>>>(out, gamma, beta);
}

// Round 6
// 9970.830 us; speedup vs baseline: 1.0365x; 1.0035x over previous
//
#include <hip/hip_runtime.h>
#include <math.h>

#define B_ 8
#define N_ 16384
#define M_ 4096
#define D_ 512
#define TPB 1024
#define PPT 16          // N_ / TPB points per thread

#define FEAT_SZ (B_ * M_ * D_)          // 16777216
#define COFF FEAT_SZ                    // coords_out
#define TOFF (FEAT_SZ + 2 * B_ * M_)    // times_out
#define POFF (TOFF + B_ * M_)           // pol_out

#define R16(F) F(0) F(1) F(2) F(3) F(4) F(5) F(6) F(7) \
               F(8) F(9) F(10) F(11) F(12) F(13) F(14) F(15)

// ---------------------------------------------------------------------------
// Kernel 1: farthest point sampling, one block per batch.
// Distance rounding verified in round 2: d2 = fma(dz,dz, fma(dx,dx, dy*dy)),
// then sqrt_rn(d2 + 1e-8); min tracked in sqrt domain (reference's exact
// formula); argmax first-index tie-break via packed u64 keys.
//
// Occupancy pinning (round-5 finding): __launch_bounds__' 2nd arg is only a
// MIN waves/EU; the AMDGPU scheduler still targets MAX occupancy (8 waves/EU
// = 2x1024 blocks) and squeezes register pressure to 512/8=64 VGPRs,
// reloading the 64-float point state from memory every iteration
// (VGPR=48-64, FETCH ~800MB across r2-r5). amdgpu_waves_per_eu(4,4) pins
// min=max=4 waves/EU (exactly one block/CU) -> pressure budget 128 VGPRs ->
// the named-scalar state (~85 live) finally stays register-resident.
// ---------------------------------------------------------------------------
__global__ __launch_bounds__(TPB)
__attribute__((amdgpu_waves_per_eu(4, 4)))
void fps_kernel(
    const float* __restrict__ coords, const float* __restrict__ times,
    int* __restrict__ idx_out)
{
    const int b = blockIdx.x;
    const int t = threadIdx.x;
    const float* cb = coords + (size_t)b * N_ * 2;
    const float* tb = times + (size_t)b * N_;

#define DECLV(i) float px##i, py##i, pt##i, s##i;
    R16(DECLV)
#undef DECLV

#define LOADV(i) { const int gi = (i) * TPB + t;                              \
        const float2 c2 = *(const float2*)(cb + 2 * (size_t)gi);              \
        px##i = c2.x; py##i = c2.y; pt##i = tb[gi]; s##i = INFINITY; }
    R16(LOADV)
#undef LOADV

    __shared__ unsigned long long sh_key[2];

    if (t == 0) {
        idx_out[b * M_] = 0;            // deterministic seed point
        sh_key[0] = 0ULL;
        sh_key[1] = 0ULL;
    }
    // seed point: broadcast load (L1-hot)
    float lx = cb[0], ly = cb[1], lt = tb[0];
    __syncthreads();

    const int lane = t & 63;

    for (int k = 1; k < M_; ++k) {
        float best = -INFINITY;
        int   bi = 0;

#define UPDV(i) {                                                             \
        const float dx = px##i - lx;                                          \
        const float dy = py##i - ly;                                          \
        const float dz = pt##i - lt;                                          \
        const float d2 = __fmaf_rn(dz, dz, __fmaf_rn(dx, dx,                  \
                                                     __fmul_rn(dy, dy)));     \
        const float sn = __fsqrt_rn(__fadd_rn(d2, 1e-8f));                    \
        s##i = fminf(s##i, sn);                                               \
        if (s##i > best) { best = s##i; bi = (i) * TPB + t; } }
        R16(UPDV)
#undef UPDV

        // pack: max s wins; tie -> max (N-1-idx) = min idx (jnp.argmax first-hit)
        unsigned long long key =
            ((unsigned long long)__float_as_uint(best) << 32) |
            (unsigned)(N_ - 1 - bi);

        // wave (64-lane) max-reduce of the packed key
#pragma unroll
        for (int off = 1; off < 64; off <<= 1) {
            unsigned long long ok = __shfl_xor(key, off);
            if (ok > key) key = ok;
        }
        if (lane == 0) atomicMax(&sh_key[k & 1], key);
        __syncthreads();

        const unsigned long long wk = sh_key[k & 1];
        const int gi = N_ - 1 - (int)(unsigned)(wk & 0xffffffffu);
        if (t == 0) {
            idx_out[b * M_ + k] = gi;
            sh_key[(k + 1) & 1] = 0ULL;   // reset other slot before BAR2: race-free
        }
        // winner's point: same-address broadcast loads, latency hides under BAR2
        lx = cb[2 * gi]; ly = cb[2 * gi + 1]; lt = tb[gi];
        __syncthreads();
    }
}

// ---------------------------------------------------------------------------
// Kernel 2: gather coords/times/polarities at sampled indices.
// ---------------------------------------------------------------------------
__global__ __launch_bounds__(256) void gather_kernel(
    const float* __restrict__ coords, const float* __restrict__ times,
    const float* __restrict__ pol, const int* __restrict__ idx,
    float* __restrict__ out)
{
    int i = blockIdx.x * 256 + threadIdx.x;       // 0 .. B_*M_-1
    if (i >= B_ * M_) return;
    int b = i >> 12;                              // / M_
    int g = b * N_ + idx[i];
    float2 c2 = *(const float2*)(coords + 2 * (size_t)g);
    *(float2*)(out + COFF + 2 * (size_t)i) = c2;
    out[TOFF + i] = times[g];
    out[POFF + i] = pol[g];
}

// ---------------------------------------------------------------------------
// Kernel 3: gathered GEMM + bias.  C[row, o] = features[src(row), :] . W[o, :]
// ---------------------------------------------------------------------------
#define BM 32
#define BN 128
#define BK 32

__global__ __launch_bounds__(256) void proj_kernel(
    const float* __restrict__ features, const float* __restrict__ W,
    const float* __restrict__ bias, const int* __restrict__ idx,
    float* __restrict__ out)
{
    __shared__ float a_lds[BK][BM + 4];
    __shared__ float w_lds[BK][BN];
    __shared__ int   src[BM];

    const int t = threadIdx.x;
    const int rowBase = blockIdx.x * BM;
    const int oBase = blockIdx.y * BN;

    if (t < BM) {
        int row = rowBase + t;
        int b = row >> 12;                // / M_
        src[t] = b * N_ + idx[row];
    }
    __syncthreads();

    const int rt = t >> 5;        // 0..7   -> rows rt*4..rt*4+3
    const int ot = t & 31;        // 0..31  -> outs ot*4..ot*4+3
    const int lr = t >> 3;        // 0..31  staging row / out
    const int lk = (t & 7) * 4;   // 0,4,...,28 staging k

    float c[4][4] = {};

    for (int kc = 0; kc < D_; kc += BK) {
        {
            float4 v = *(const float4*)(features + (size_t)src[lr] * D_ + kc + lk);
            a_lds[lk + 0][lr] = v.x; a_lds[lk + 1][lr] = v.y;
            a_lds[lk + 2][lr] = v.z; a_lds[lk + 3][lr] = v.w;
        }
#pragma unroll
        for (int p = 0; p < 4; ++p) {
            int o = p * 32 + lr;
            float4 v = *(const float4*)(W + (size_t)(oBase + o) * D_ + kc + lk);
            w_lds[lk + 0][o] = v.x; w_lds[lk + 1][o] = v.y;
            w_lds[lk + 2][o] = v.z; w_lds[lk + 3][o] = v.w;
        }
        __syncthreads();

#pragma unroll
        for (int k = 0; k < BK; ++k) {
            float4 af = *(const float4*)&a_lds[k][rt * 4];
            float4 wf = *(const float4*)&w_lds[k][ot * 4];
            float av[4] = { af.x, af.y, af.z, af.w };
            float wv[4] = { wf.x, wf.y, wf.z, wf.w };
#pragma unroll
            for (int ri = 0; ri < 4; ++ri)
#pragma unroll
                for (int oi = 0; oi < 4; ++oi)
                    c[ri][oi] = fmaf(av[ri], wv[oi], c[ri][oi]);
        }
        __syncthreads();
    }

    float4 bv = *(const float4*)(bias + oBase + ot * 4);
    float bvv[4] = { bv.x, bv.y, bv.z, bv.w };
#pragma unroll
    for (int ri = 0; ri < 4; ++ri) {
        int row = rowBase + rt * 4 + ri;
        float4 o4;
        o4.x = c[ri][0] + bvv[0];
        o4.y = c[ri][1] + bvv[1];
        o4.z = c[ri][2] + bvv[2];
        o4.w = c[ri][3] + bvv[3];
        *(float4*)(out + (size_t)row * D_ + oBase + ot * 4) = o4;
    }
}

// ---------------------------------------------------------------------------
// Kernel 4: LayerNorm in place over the proj output. One wave per row.
// ---------------------------------------------------------------------------
__global__ __launch_bounds__(256) void ln_kernel(
    float* __restrict__ out, const float* __restrict__ gamma,
    const float* __restrict__ beta)
{
    const int w = threadIdx.x >> 6;
    const int lane = threadIdx.x & 63;
    const size_t row = (size_t)blockIdx.x * 4 + w;
    float* p = out + row * D_;

    float4 v0 = *(const float4*)(p + lane * 8);
    float4 v1 = *(const float4*)(p + lane * 8 + 4);
    float x[8] = { v0.x, v0.y, v0.z, v0.w, v1.x, v1.y, v1.z, v1.w };

    float sum = 0.f;
#pragma unroll
    for (int i = 0; i < 8; ++i) sum += x[i];
#pragma unroll
    for (int off = 1; off < 64; off <<= 1) sum += __shfl_xor(sum, off);
    const float mu = sum * (1.0f / 512.0f);

    float sq = 0.f;
#pragma unroll
    for (int i = 0; i < 8; ++i) { float d = x[i] - mu; sq = fmaf(d, d, sq); }
#pragma unroll
    for (int off = 1; off < 64; off <<= 1) sq += __shfl_xor(sq, off);
    const float inv = rsqrtf(sq * (1.0f / 512.0f) + 1e-5f);

    float4 g0 = *(const float4*)(gamma + lane * 8);
    float4 g1 = *(const float4*)(gamma + lane * 8 + 4);
    float4 b0 = *(const float4*)(beta + lane * 8);
    float4 b1 = *(const float4*)(beta + lane * 8 + 4);
    float g[8] = { g0.x, g0.y, g0.z, g0.w, g1.x, g1.y, g1.z, g1.w };
    float be[8] = { b0.x, b0.y, b0.z, b0.w, b1.x, b1.y, b1.z, b1.w };

    float y[8];
#pragma unroll
    for (int i = 0; i < 8; ++i) y[i] = fmaf((x[i] - mu) * inv, g[i], be[i]);

    float4 o0 = { y[0], y[1], y[2], y[3] };
    float4 o1 = { y[4], y[5], y[6], y[7] };
    *(float4*)(p + lane * 8) = o0;
    *(float4*)(p + lane * 8 + 4) = o1;
}

// ---------------------------------------------------------------------------
extern "C" void kernel_launch(void* const* d_in, const int* in_sizes, int n_in,
                              void* d_out, int out_size, void* d_ws, size_t ws_size,
                              hipStream_t stream)
{
    const float* features   = (const float*)d_in[0];
    const float* coords     = (const float*)d_in[1];
    const float* times      = (const float*)d_in[2];
    const float* polarities = (const float*)d_in[3];
    const float* W          = (const float*)d_in[4];
    const float* bias       = (const float*)d_in[5];
    const float* gamma      = (const float*)d_in[6];
    const float* beta       = (const float*)d_in[7];
    float* out = (float*)d_out;

    int* idx = (int*)d_ws;                        // B_*M_ ints = 128 KiB scratch

    fps_kernel<<<B_, TPB, 0, stream>>>(coords, times, idx);

    gather_kernel<<<(B_ * M_ + 255) / 256, 256, 0, stream>>>(
        coords, times, polarities, idx, out);

    dim3 pgrid(B_ * M_ / BM, D_ / BN);            // (1024, 4)
    proj_kernel<<<pgrid, 256, 0, stream>>>(features, W, bias, idx, out);

    ln_kernel<<<B_ * M_ / 4, 256, 0, stream>>>(out, gamma, beta);
}

// Round 7
// 8125.102 us; speedup vs baseline: 1.2720x; 1.2272x over previous
//
#include <hip/hip_runtime.h>
#include <math.h>

#define B_ 8
#define N_ 16384
#define M_ 4096
#define D_ 512
#define TPB 1024
#define PPT 16          // N_ / TPB points per thread

#define FEAT_SZ (B_ * M_ * D_)          // 16777216
#define COFF FEAT_SZ                    // coords_out
#define TOFF (FEAT_SZ + 2 * B_ * M_)    // times_out
#define POFF (TOFF + B_ * M_)           // pol_out

#define R16(F) F(0) F(1) F(2) F(3) F(4) F(5) F(6) F(7) \
               F(8) F(9) F(10) F(11) F(12) F(13) F(14) F(15)

// ---------------------------------------------------------------------------
// Kernel 1: farthest point sampling, one block per batch.
//
// Bit-exact chain (verified round 2): d2 = fma(dz,dz, fma(dx,dx, dy*dy));
// s = sqrt_rn(fadd_rn(d2, 1e-8)). Min is tracked in d2 domain (fminf commutes
// with the weakly-monotone rounded sqrt chain, so the s values are identical
// to the reference's sqrt-domain min). Argmax must be in s-domain with
// first-index tie-break (distinct d2 can collapse to equal s): we take ONE
// sqrt of the thread max, and run a guarded fixup when any other slot is
// within 32 ulps of the max (sqrt preimage width is <= ~4 ulps) to find the
// true first index with equal s. Cross-thread: packed u64 (s_bits<<32 |
// N-1-idx) max-reduce = (max s, min index).
//
// Perf history: r3-r6 proved the compiler re-loads the loop-invariant point
// set from L2 every iteration instead of keeping it in VGPRs (VGPR stuck at
// 48-64; only the loop-carried mins stayed resident). The asm "+v" pins make
// each loaded value an inline-asm def — not rematerializable — forcing
// register residency (~82 live, budget 128 via waves_per_eu(4,4)).
// ---------------------------------------------------------------------------
__global__ __launch_bounds__(TPB)
__attribute__((amdgpu_waves_per_eu(4, 4)))
void fps_kernel(
    const float* __restrict__ coords, const float* __restrict__ times,
    int* __restrict__ idx_out)
{
    const int b = blockIdx.x;
    const int t = threadIdx.x;
    const float* cb = coords + (size_t)b * N_ * 2;
    const float* tb = times + (size_t)b * N_;

#define DECLV(i) float px##i, py##i, pt##i, m##i;
    R16(DECLV)
#undef DECLV

#define LOADV(i) { const int gi = (i) * TPB + t;                              \
        const float2 c2 = *(const float2*)(cb + 2 * (size_t)gi);              \
        px##i = c2.x; py##i = c2.y; pt##i = tb[gi]; m##i = INFINITY; }
    R16(LOADV)
#undef LOADV

    // Pin the invariant point state into VGPRs: inline-asm defs cannot be
    // rematerialized as loads inside the loop.
#define PINV(i) asm("" : "+v"(px##i), "+v"(py##i), "+v"(pt##i));
    R16(PINV)
#undef PINV

    __shared__ unsigned long long red[2][16];   // per-wave keys, parity dbuf

    if (t == 0) idx_out[b * M_] = 0;            // deterministic seed point
    float lx = cb[0], ly = cb[1], lt = tb[0];
    __syncthreads();

    const int wave = t >> 6;
    const int lane = t & 63;

    for (int k = 1; k < M_; ++k) {
        float bm = -INFINITY;
        int   bj = 0;

        // min-update in d2 domain + first-occurrence thread argmax over m
#define UPDV(i) {                                                             \
        const float dx = px##i - lx;                                          \
        const float dy = py##i - ly;                                          \
        const float dz = pt##i - lt;                                          \
        const float d2 = __fmaf_rn(dz, dz, __fmaf_rn(dx, dx,                  \
                                                     __fmul_rn(dy, dy)));     \
        m##i = fminf(m##i, d2);                                               \
        if (m##i > bm) { bm = m##i; bj = (i); } }
        R16(UPDV)
#undef UPDV

        const float s_best = __fsqrt_rn(__fadd_rn(bm, 1e-8f));

        // s-tie fixup guard: slots within 32 ulps of bm could share s_best
        const unsigned bmu = __float_as_uint(bm);
        const float thresh = __uint_as_float(bmu >= 32u ? bmu - 32u : 0u);
        float cnt = 0.f;
#define CNTV(i) cnt += (m##i >= thresh) ? 1.0f : 0.0f;
        R16(CNTV)
#undef CNTV

        int fj = bj;
        if (cnt > 1.5f) {      // rare: verify candidates, take min slot index
#define FIXV(i) if (m##i >= thresh) {                                         \
            const float si = __fsqrt_rn(__fadd_rn(m##i, 1e-8f));              \
            if (si == s_best && (i) < fj) fj = (i); }
            R16(FIXV)
#undef FIXV
        }

        // pack: max s wins; tie -> max (N-1-idx) = min idx (jnp.argmax first-hit)
        unsigned long long key =
            ((unsigned long long)__float_as_uint(s_best) << 32) |
            (unsigned)(N_ - 1 - (fj * TPB + t));

        // wave (64-lane) max-reduce of the packed key
#pragma unroll
        for (int off = 1; off < 64; off <<= 1) {
            unsigned long long ok = __shfl_xor(key, off);
            if (ok > key) key = ok;
        }
        if (lane == 0) red[k & 1][wave] = key;
        __syncthreads();

        // all threads redundantly scan the 16 wave keys (broadcast reads)
        unsigned long long wk = red[k & 1][0];
#pragma unroll
        for (int w = 1; w < 16; ++w) {
            const unsigned long long ok = red[k & 1][w];
            if (ok > wk) wk = ok;
        }
        const int gi = N_ - 1 - (int)(unsigned)(wk & 0xffffffffu);
        if (t == 0) idx_out[b * M_ + k] = gi;
        // winner's point: same-address broadcast loads (L1/L2-hot)
        lx = cb[2 * gi]; ly = cb[2 * gi + 1]; lt = tb[gi];
        // no second barrier: next iteration writes the other parity slot
    }
}

// ---------------------------------------------------------------------------
// Kernel 2: gather coords/times/polarities at sampled indices.
// ---------------------------------------------------------------------------
__global__ __launch_bounds__(256) void gather_kernel(
    const float* __restrict__ coords, const float* __restrict__ times,
    const float* __restrict__ pol, const int* __restrict__ idx,
    float* __restrict__ out)
{
    int i = blockIdx.x * 256 + threadIdx.x;       // 0 .. B_*M_-1
    if (i >= B_ * M_) return;
    int b = i >> 12;                              // / M_
    int g = b * N_ + idx[i];
    float2 c2 = *(const float2*)(coords + 2 * (size_t)g);
    *(float2*)(out + COFF + 2 * (size_t)i) = c2;
    out[TOFF + i] = times[g];
    out[POFF + i] = pol[g];
}

// ---------------------------------------------------------------------------
// Kernel 3: gathered GEMM + bias.  C[row, o] = features[src(row), :] . W[o, :]
// ---------------------------------------------------------------------------
#define BM 32
#define BN 128
#define BK 32

__global__ __launch_bounds__(256) void proj_kernel(
    const float* __restrict__ features, const float* __restrict__ W,
    const float* __restrict__ bias, const int* __restrict__ idx,
    float* __restrict__ out)
{
    __shared__ float a_lds[BK][BM + 4];
    __shared__ float w_lds[BK][BN];
    __shared__ int   src[BM];

    const int t = threadIdx.x;
    const int rowBase = blockIdx.x * BM;
    const int oBase = blockIdx.y * BN;

    if (t < BM) {
        int row = rowBase + t;
        int b = row >> 12;                // / M_
        src[t] = b * N_ + idx[row];
    }
    __syncthreads();

    const int rt = t >> 5;        // 0..7   -> rows rt*4..rt*4+3
    const int ot = t & 31;        // 0..31  -> outs ot*4..ot*4+3
    const int lr = t >> 3;        // 0..31  staging row / out
    const int lk = (t & 7) * 4;   // 0,4,...,28 staging k

    float c[4][4] = {};

    for (int kc = 0; kc < D_; kc += BK) {
        {
            float4 v = *(const float4*)(features + (size_t)src[lr] * D_ + kc + lk);
            a_lds[lk + 0][lr] = v.x; a_lds[lk + 1][lr] = v.y;
            a_lds[lk + 2][lr] = v.z; a_lds[lk + 3][lr] = v.w;
        }
#pragma unroll
        for (int p = 0; p < 4; ++p) {
            int o = p * 32 + lr;
            float4 v = *(const float4*)(W + (size_t)(oBase + o) * D_ + kc + lk);
            w_lds[lk + 0][o] = v.x; w_lds[lk + 1][o] = v.y;
            w_lds[lk + 2][o] = v.z; w_lds[lk + 3][o] = v.w;
        }
        __syncthreads();

#pragma unroll
        for (int k = 0; k < BK; ++k) {
            float4 af = *(const float4*)&a_lds[k][rt * 4];
            float4 wf = *(const float4*)&w_lds[k][ot * 4];
            float av[4] = { af.x, af.y, af.z, af.w };
            float wv[4] = { wf.x, wf.y, wf.z, wf.w };
#pragma unroll
            for (int ri = 0; ri < 4; ++ri)
#pragma unroll
                for (int oi = 0; oi < 4; ++oi)
                    c[ri][oi] = fmaf(av[ri], wv[oi], c[ri][oi]);
        }
        __syncthreads();
    }

    float4 bv = *(const float4*)(bias + oBase + ot * 4);
    float bvv[4] = { bv.x, bv.y, bv.z, bv.w };
#pragma unroll
    for (int ri = 0; ri < 4; ++ri) {
        int row = rowBase + rt * 4 + ri;
        float4 o4;
        o4.x = c[ri][0] + bvv[0];
        o4.y = c[ri][1] + bvv[1];
        o4.z = c[ri][2] + bvv[2];
        o4.w = c[ri][3] + bvv[3];
        *(float4*)(out + (size_t)row * D_ + oBase + ot * 4) = o4;
    }
}

// ---------------------------------------------------------------------------
// Kernel 4: LayerNorm in place over the proj output. One wave per row.
// ---------------------------------------------------------------------------
__global__ __launch_bounds__(256) void ln_kernel(
    float* __restrict__ out, const float* __restrict__ gamma,
    const float* __restrict__ beta)
{
    const int w = threadIdx.x >> 6;
    const int lane = threadIdx.x & 63;
    const size_t row = (size_t)blockIdx.x * 4 + w;
    float* p = out + row * D_;

    float4 v0 = *(const float4*)(p + lane * 8);
    float4 v1 = *(const float4*)(p + lane * 8 + 4);
    float x[8] = { v0.x, v0.y, v0.z, v0.w, v1.x, v1.y, v1.z, v1.w };

    float sum = 0.f;
#pragma unroll
    for (int i = 0; i < 8; ++i) sum += x[i];
#pragma unroll
    for (int off = 1; off < 64; off <<= 1) sum += __shfl_xor(sum, off);
    const float mu = sum * (1.0f / 512.0f);

    float sq = 0.f;
#pragma unroll
    for (int i = 0; i < 8; ++i) { float d = x[i] - mu; sq = fmaf(d, d, sq); }
#pragma unroll
    for (int off = 1; off < 64; off <<= 1) sq += __shfl_xor(sq, off);
    const float inv = rsqrtf(sq * (1.0f / 512.0f) + 1e-5f);

    float4 g0 = *(const float4*)(gamma + lane * 8);
    float4 g1 = *(const float4*)(gamma + lane * 8 + 4);
    float4 b0 = *(const float4*)(beta + lane * 8);
    float4 b1 = *(const float4*)(beta + lane * 8 + 4);
    float g[8] = { g0.x, g0.y, g0.z, g0.w, g1.x, g1.y, g1.z, g1.w };
    float be[8] = { b0.x, b0.y, b0.z, b0.w, b1.x, b1.y, b1.z, b1.w };

    float y[8];
#pragma unroll
    for (int i = 0; i < 8; ++i) y[i] = fmaf((x[i] - mu) * inv, g[i], be[i]);

    float4 o0 = { y[0], y[1], y[2], y[3] };
    float4 o1 = { y[4], y[5], y[6], y[7] };
    *(float4*)(p + lane * 8) = o0;
    *(float4*)(p + lane * 8 + 4) = o1;
}

// ---------------------------------------------------------------------------
extern "C" void kernel_launch(void* const* d_in, const int* in_sizes, int n_in,
                              void* d_out, int out_size, void* d_ws, size_t ws_size,
                              hipStream_t stream)
{
    const float* features   = (const float*)d_in[0];
    const float* coords     = (const float*)d_in[1];
    const float* times      = (const float*)d_in[2];
    const float* polarities = (const float*)d_in[3];
    const float* W          = (const float*)d_in[4];
    const float* bias       = (const float*)d_in[5];
    const float* gamma      = (const float*)d_in[6];
    const float* beta       = (const float*)d_in[7];
    float* out = (float*)d_out;

    int* idx = (int*)d_ws;                        // B_*M_ ints = 128 KiB scratch

    fps_kernel<<<B_, TPB, 0, stream>>>(coords, times, idx);

    gather_kernel<<<(B_ * M_ + 255) / 256, 256, 0, stream>>>(
        coords, times, polarities, idx, out);

    dim3 pgrid(B_ * M_ / BM, D_ / BN);            // (1024, 4)
    proj_kernel<<<pgrid, 256, 0, stream>>>(features, W, bias, idx, out);

    ln_kernel<<<B_ * M_ / 4, 256, 0, stream>>>(out, gamma, beta);
}